// Round 5
// baseline (91.370 us; speedup 1.0000x reference)
//
#include <hip/hip_runtime.h>
#include <hip/hip_bf16.h>

#define DD 512
#define NN 8
#define LL0 128
#define LL1 256

// 2 * log2(e): pre-scale factor so tanh(t) can use v_exp_f32 (2^x) directly.
#define LOG2E2 2.8853900817779268f

// split-K partial plane stride (floats): 3072 rows x 512 e
#define PSTR ((size_t)3072 * 512)

__device__ __forceinline__ float fexp2(float x) {
#if __has_builtin(__builtin_amdgcn_exp2f)
    return __builtin_amdgcn_exp2f(x);
#else
    float r; asm("v_exp_f32 %0, %1" : "=v"(r) : "v"(x)); return r;
#endif
}
__device__ __forceinline__ float frcp(float x) {
#if __has_builtin(__builtin_amdgcn_rcpf)
    return __builtin_amdgcn_rcpf(x);
#else
    float r; asm("v_rcp_f32 %0, %1" : "=v"(r) : "v"(x)); return r;
#endif
}

// sigma2(t2) = 1/(2^t2 + 1), where t2 = 2*log2e*t.  tanh(t) = 1 - 2*sigma2.
__device__ __forceinline__ float sig2(float t2) {
    return frcp(fexp2(t2) + 1.0f);
}

// ---------------------------------------------------------------------------
// Kernel 0: mask compaction (one block per n).
// bidx[n][j] = j-th valid b (padded with 0), jinv[n][b] = j or -1, cnt[n].
// ---------------------------------------------------------------------------
__global__ __launch_bounds__(256) void compact_kernel(
    const int* __restrict__ mask, int* __restrict__ bidx,
    int* __restrict__ jinv, int* __restrict__ cnt)
{
    __shared__ int wsum[4];
    int n = blockIdx.x, b = threadIdx.x;
    int v = (mask[n * LL1 + b] != 0) ? 1 : 0;
    unsigned long long bal = __ballot(v);
    int lane = b & 63, wv = b >> 6;
    int wpre = __popcll(bal & ((1ull << lane) - 1ull));
    if (lane == 63) wsum[wv] = wpre + v;     // wave total
    bidx[n * LL1 + b] = 0;                   // padding default
    __syncthreads();
    int base = 0;
    #pragma unroll
    for (int i = 0; i < 4; ++i) base += (i < wv) ? wsum[i] : 0;
    int pos = base + wpre;
    if (v) {
        bidx[n * LL1 + pos] = b;
        jinv[n * LL1 + b] = pos;
    } else {
        jinv[n * LL1 + b] = -1;
    }
    if (b == 255) cnt[n] = pos + v;          // total valid count
}

// ---------------------------------------------------------------------------
// Kernel 1: fused projections, split-K=2.  (measured ~34 us; unchanged)
// Tile 64(M) x 64(e), K-chunk 32, 4x4 micro-tile; LDS transposed [k][row].
// Grid (48, 8, 2) = 768 blocks = 3.0/CU exact.
// ---------------------------------------------------------------------------
__global__ __launch_bounds__(256, 3) void proj_kernel(
    const float* __restrict__ x, const float* __restrict__ m,
    const float* __restrict__ W, float* __restrict__ pp)
{
    __shared__ float At[32][68];
    __shared__ float Bt[32][68];

    int row0 = blockIdx.x * 64;
    int e0   = blockIdx.y * 64;
    int kb   = blockIdx.z * 256;   // K-half base

    bool isx = row0 < (NN * LL0);
    const float* A  = (isx ? x + (size_t)row0 * DD
                           : m + (size_t)(row0 - NN * LL0) * DD) + kb;
    const float* Wp = W + (size_t)e0 * (2 * DD) + (isx ? 0 : DD) + kb;

    int t  = threadIdx.x;
    int lr = t >> 2;              // 0..63
    int kc = (t & 3) * 8;         // 0,8,16,24
    int ty = t >> 4, tx = t & 15;

    const float* Ap = A  + (size_t)lr * DD + kc;
    const float* Bp = Wp + (size_t)lr * (2 * DD) + kc;

    float4 ar0 = *(const float4*)(Ap);
    float4 ar1 = *(const float4*)(Ap + 4);
    float4 br0 = *(const float4*)(Bp);
    float4 br1 = *(const float4*)(Bp + 4);

    float acc[4][4] = {};

    for (int kt = 0; kt < 8; ++kt) {
        if (kt) __syncthreads();
        At[kc + 0][lr] = ar0.x; At[kc + 1][lr] = ar0.y;
        At[kc + 2][lr] = ar0.z; At[kc + 3][lr] = ar0.w;
        At[kc + 4][lr] = ar1.x; At[kc + 5][lr] = ar1.y;
        At[kc + 6][lr] = ar1.z; At[kc + 7][lr] = ar1.w;
        Bt[kc + 0][lr] = br0.x; Bt[kc + 1][lr] = br0.y;
        Bt[kc + 2][lr] = br0.z; Bt[kc + 3][lr] = br0.w;
        Bt[kc + 4][lr] = br1.x; Bt[kc + 5][lr] = br1.y;
        Bt[kc + 6][lr] = br1.z; Bt[kc + 7][lr] = br1.w;
        if (kt < 7) {
            int ko = (kt + 1) * 32;
            ar0 = *(const float4*)(Ap + ko);
            ar1 = *(const float4*)(Ap + ko + 4);
            br0 = *(const float4*)(Bp + ko);
            br1 = *(const float4*)(Bp + ko + 4);
        }
        __syncthreads();

        #pragma unroll
        for (int kk = 0; kk < 32; ++kk) {
            float4 av = *(const float4*)&At[kk][ty * 4];
            float4 bv = *(const float4*)&Bt[kk][tx * 4];
            acc[0][0] = fmaf(av.x, bv.x, acc[0][0]);
            acc[0][1] = fmaf(av.x, bv.y, acc[0][1]);
            acc[0][2] = fmaf(av.x, bv.z, acc[0][2]);
            acc[0][3] = fmaf(av.x, bv.w, acc[0][3]);
            acc[1][0] = fmaf(av.y, bv.x, acc[1][0]);
            acc[1][1] = fmaf(av.y, bv.y, acc[1][1]);
            acc[1][2] = fmaf(av.y, bv.z, acc[1][2]);
            acc[1][3] = fmaf(av.y, bv.w, acc[1][3]);
            acc[2][0] = fmaf(av.z, bv.x, acc[2][0]);
            acc[2][1] = fmaf(av.z, bv.y, acc[2][1]);
            acc[2][2] = fmaf(av.z, bv.z, acc[2][2]);
            acc[2][3] = fmaf(av.z, bv.w, acc[2][3]);
            acc[3][0] = fmaf(av.w, bv.x, acc[3][0]);
            acc[3][1] = fmaf(av.w, bv.y, acc[3][1]);
            acc[3][2] = fmaf(av.w, bv.z, acc[3][2]);
            acc[3][3] = fmaf(av.w, bv.w, acc[3][3]);
        }
    }

    float* outp = pp + (size_t)blockIdx.z * PSTR
                     + (size_t)row0 * DD + e0 + tx * 4;
    #pragma unroll
    for (int i = 0; i < 4; ++i) {
        float4 v = make_float4(acc[i][0], acc[i][1], acc[i][2], acc[i][3]);
        *(float4*)(outp + (size_t)(ty * 4 + i) * DD) = v;
    }
}

// ---------------------------------------------------------------------------
// Kernel 1b: split-K reduce (2 planes) + bias + LOG2E2 scale. (unchanged)
// ---------------------------------------------------------------------------
__global__ __launch_bounds__(256) void reduce_kernel(
    const float* __restrict__ pp, const float* __restrict__ Wb,
    float* __restrict__ xpb_base)
{
    size_t f = (size_t)blockIdx.x * 256 + threadIdx.x;   // float4 index
    const float4* p4 = (const float4*)pp;
    float4 v0 = p4[f];
    float4 v1 = p4[f + PSTR / 4];
    float4 s = make_float4(v0.x + v1.x, v0.y + v1.y, v0.z + v1.z, v0.w + v1.w);
    size_t off = f * 4;
    if (off < (size_t)NN * LL0 * DD) {   // x-rows: add bias
        float4 wb = *(const float4*)(Wb + (off & (DD - 1)));
        s.x += wb.x; s.y += wb.y; s.z += wb.z; s.w += wb.w;
    }
    s.x *= LOG2E2; s.y *= LOG2E2; s.z *= LOG2E2; s.w *= LOG2E2;
    ((float4*)xpb_base)[f] = s;
}

// ---------------------------------------------------------------------------
// Kernel 2: logits on COMPACTED b only.
//   wpart[dc][n][a][j] = sum_{d in chunk dc} V[d]/(2^(xp[n,a,d]+mp[n,bidx[j],d])+1)
// Tile 32a x 32j x 64d, 2x2 micro-tile. Blocks with jbase >= cnt[n] exit.
// Grid (8, 32, 8) = 2048 static, ~cnt/256 fraction active (~4.3/CU).
// ---------------------------------------------------------------------------
__global__ __launch_bounds__(256, 8) void logits_kernel(
    const float* __restrict__ xpb, const float* __restrict__ mp,
    const float* __restrict__ Vw, const int* __restrict__ bidx,
    const int* __restrict__ cnt, float* __restrict__ wpart)
{
    __shared__ __attribute__((aligned(16))) float xs[32][68];
    __shared__ __attribute__((aligned(16))) float ms[32][68];
    __shared__ __attribute__((aligned(16))) float vsh[64];

    int n  = blockIdx.z;
    int bt = blockIdx.x;          // compact j-tile of 32
    int at = blockIdx.y & 3;      // 0..3 (32 a-rows)
    int dc = blockIdx.y >> 2;     // 0..7 (64 d)
    int jbase = bt * 32;
    if (jbase >= cnt[n]) return;  // tile fully beyond valid count

    int tid = threadIdx.x;
    int ty = tid >> 4, tx = tid & 15;

    const float* xrow = xpb + (size_t)(n * LL0 + at * 32) * DD + dc * 64;

    {
        int r  = tid >> 3;            // 0..31
        int c8 = (tid & 7) * 8;       // 0..56
        *(float4*)&xs[r][c8]     = *(const float4*)(xrow + (size_t)r * DD + c8);
        *(float4*)&xs[r][c8 + 4] = *(const float4*)(xrow + (size_t)r * DD + c8 + 4);
        int bj = bidx[n * LL1 + jbase + r];          // gather index (pad -> 0)
        const float* mrow = mp + ((size_t)n * LL1 + bj) * DD + dc * 64;
        *(float4*)&ms[r][c8]     = *(const float4*)(mrow + c8);
        *(float4*)&ms[r][c8 + 4] = *(const float4*)(mrow + c8 + 4);
        if (tid < 16)
            *(float4*)&vsh[tid * 4] = *(const float4*)(Vw + dc * 64 + tid * 4);
    }
    __syncthreads();

    float a00 = 0.f, a01 = 0.f, a10 = 0.f, a11 = 0.f;

    #pragma unroll 4
    for (int k4 = 0; k4 < 16; ++k4) {
        float4 xa = *(const float4*)&xs[ty][k4 * 4];
        float4 xb = *(const float4*)&xs[ty + 16][k4 * 4];
        float4 ma = *(const float4*)&ms[tx][k4 * 4];
        float4 mb = *(const float4*)&ms[tx + 16][k4 * 4];
        float4 vv = *(const float4*)&vsh[k4 * 4];

        a00 = fmaf(vv.x, sig2(xa.x + ma.x), a00);
        a00 = fmaf(vv.y, sig2(xa.y + ma.y), a00);
        a00 = fmaf(vv.z, sig2(xa.z + ma.z), a00);
        a00 = fmaf(vv.w, sig2(xa.w + ma.w), a00);

        a01 = fmaf(vv.x, sig2(xa.x + mb.x), a01);
        a01 = fmaf(vv.y, sig2(xa.y + mb.y), a01);
        a01 = fmaf(vv.z, sig2(xa.z + mb.z), a01);
        a01 = fmaf(vv.w, sig2(xa.w + mb.w), a01);

        a10 = fmaf(vv.x, sig2(xb.x + ma.x), a10);
        a10 = fmaf(vv.y, sig2(xb.y + ma.y), a10);
        a10 = fmaf(vv.z, sig2(xb.z + ma.z), a10);
        a10 = fmaf(vv.w, sig2(xb.w + ma.w), a10);

        a11 = fmaf(vv.x, sig2(xb.x + mb.x), a11);
        a11 = fmaf(vv.y, sig2(xb.y + mb.y), a11);
        a11 = fmaf(vv.z, sig2(xb.z + mb.z), a11);
        a11 = fmaf(vv.w, sig2(xb.w + mb.w), a11);
    }

    const size_t P = (size_t)NN * LL0 * LL1;
    float* wp = wpart + (size_t)dc * P + ((size_t)n * LL0 + at * 32) * LL1;
    wp[(size_t)ty * LL1 + jbase + tx]             = a00;
    wp[(size_t)ty * LL1 + jbase + tx + 16]        = a01;
    wp[(size_t)(ty + 16) * LL1 + jbase + tx]      = a10;
    wp[(size_t)(ty + 16) * LL1 + jbase + tx + 16] = a11;
}

// ---------------------------------------------------------------------------
// Kernel 3: masked softmax. Gathers the 8 compact-plane partials via jinv,
// applies -2 scale, softmax over valid b (masked -> exactly 0), writes the
// DENSE result into plane 0 of wpart (consumed by vgemm).
// ---------------------------------------------------------------------------
__global__ __launch_bounds__(256) void softmax_kernel(
    float* __restrict__ wpart, const int* __restrict__ jinv)
{
    __shared__ float red[4];
    __shared__ float red2[4];
    const size_t P = (size_t)NN * LL0 * LL1;
    int row = blockIdx.x;          // n*L0 + a
    int n = row >> 7;
    int b = threadIdx.x;
    size_t rowoff = (size_t)row * LL1;

    int j = jinv[n * LL1 + b];
    float w = -1e30f;
    if (j >= 0) {
        float s8 = 0.f;
        #pragma unroll
        for (int p = 0; p < 8; ++p) s8 += wpart[(size_t)p * P + rowoff + j];
        w = -2.0f * s8;
    }

    float mx = w;
    #pragma unroll
    for (int off = 32; off; off >>= 1) mx = fmaxf(mx, __shfl_xor(mx, off));
    int wv = threadIdx.x >> 6;
    if ((threadIdx.x & 63) == 0) red[wv] = mx;
    __syncthreads();
    mx = fmaxf(fmaxf(red[0], red[1]), fmaxf(red[2], red[3]));

    float e = (j >= 0) ? __expf(w - mx) : 0.f;
    float s = e;
    #pragma unroll
    for (int off = 32; off; off >>= 1) s += __shfl_xor(s, off);
    if ((threadIdx.x & 63) == 0) red2[wv] = s;
    __syncthreads();
    s = red2[0] + red2[1] + red2[2] + red2[3];

    wpart[rowoff + b] = e / s;     // dense write into plane 0 (safe: reads done)
}

// ---------------------------------------------------------------------------
// Kernel 4: v[n,a,d] = sum_b w[n,a,b] * m[n,b,d]. (unchanged; masked w == 0)
// ---------------------------------------------------------------------------
__global__ __launch_bounds__(256) void vgemm_kernel(
    const float* __restrict__ wbuf, const float* __restrict__ m,
    float* __restrict__ out)
{
    __shared__ float ws_t[64][17];
    __shared__ float ms_t[16][65];

    int n = blockIdx.z;
    int a0 = blockIdx.y * 64;
    int d0 = blockIdx.x * 64;
    int tid = threadIdx.x;
    int ty = tid >> 4, tx = tid & 15;

    const float* wrow = wbuf + ((size_t)n * LL0 + a0) * LL1;
    const float* mrow = m + (size_t)n * LL1 * DD;

    float acc[4][4] = {};
    for (int k0 = 0; k0 < LL1; k0 += 16) {
        {
            int lr = tid >> 2, lc = (tid & 3) * 4;
            float4 wv = *(const float4*)(wrow + (size_t)lr * LL1 + k0 + lc);
            ws_t[lr][lc + 0] = wv.x; ws_t[lr][lc + 1] = wv.y;
            ws_t[lr][lc + 2] = wv.z; ws_t[lr][lc + 3] = wv.w;
        }
        {
            int lr = tid >> 4, lc = (tid & 15) * 4;
            float4 mv = *(const float4*)(mrow + (size_t)(k0 + lr) * DD + d0 + lc);
            ms_t[lr][lc + 0] = mv.x; ms_t[lr][lc + 1] = mv.y;
            ms_t[lr][lc + 2] = mv.z; ms_t[lr][lc + 3] = mv.w;
        }
        __syncthreads();
        #pragma unroll
        for (int kk = 0; kk < 16; ++kk) {
            float a_[4], b_[4];
            #pragma unroll
            for (int i = 0; i < 4; ++i) a_[i] = ws_t[ty * 4 + i][kk];
            #pragma unroll
            for (int j = 0; j < 4; ++j) b_[j] = ms_t[kk][tx * 4 + j];
            #pragma unroll
            for (int i = 0; i < 4; ++i)
                #pragma unroll
                for (int j = 0; j < 4; ++j)
                    acc[i][j] = fmaf(a_[i], b_[j], acc[i][j]);
        }
        __syncthreads();
    }
    #pragma unroll
    for (int i = 0; i < 4; ++i)
        #pragma unroll
        for (int j = 0; j < 4; ++j)
            out[((size_t)n * LL0 + a0 + ty * 4 + i) * DD + d0 + tx * 4 + j] = acc[i][j];
}

extern "C" void kernel_launch(void* const* d_in, const int* in_sizes, int n_in,
                              void* d_out, int out_size, void* d_ws, size_t ws_size,
                              hipStream_t stream) {
    const float* x    = (const float*)d_in[0];
    const float* m    = (const float*)d_in[1];
    const int*   mask = (const int*)d_in[2];
    const float* W_w  = (const float*)d_in[3];
    const float* W_b  = (const float*)d_in[4];
    const float* V_w  = (const float*)d_in[5];
    const float* V_b  = (const float*)d_in[6];
    (void)V_b; // additive constant — cancels under softmax shift-invariance
    float* out = (float*)d_out;

    // Workspace layout (floats):
    //   xpb    : 8*128*512            =  524288
    //   mp     : 8*256*512            = 1048576   (contiguous after xpb)
    //   region : max(pp 2*3072*512 = 3145728, wpart 8*8*128*256 = 2097152)
    //   ints   : bidx 2048 + jinv 2048 + cnt 8
    // Total: ~18.9 MB + 16 KB
    float* xpb    = (float*)d_ws;
    float* mp     = xpb + (size_t)NN * LL0 * DD;
    float* region = mp + (size_t)NN * LL1 * DD;
    float* pp     = region;
    float* wpart  = region;
    int*   bidx   = (int*)(region + 2 * PSTR);
    int*   jinv   = bidx + NN * LL1;
    int*   cnt    = jinv + NN * LL1;

    compact_kernel<<<dim3(8), 256, 0, stream>>>(mask, bidx, jinv, cnt);
    proj_kernel<<<dim3(48, 8, 2), 256, 0, stream>>>(x, m, W_w, pp);
    reduce_kernel<<<dim3(1536), 256, 0, stream>>>(pp, W_b, xpb);
    logits_kernel<<<dim3(8, 32, 8), 256, 0, stream>>>(xpb, mp, V_w, bidx, cnt, wpart);
    softmax_kernel<<<dim3(1024), 256, 0, stream>>>(wpart, jinv);
    vgemm_kernel<<<dim3(8, 2, 8), 256, 0, stream>>>(wpart, m, out);
}

// Round 6
// 89.766 us; speedup vs baseline: 1.0179x; 1.0179x over previous
//
#include <hip/hip_runtime.h>
#include <hip/hip_bf16.h>

#define DD 512
#define NN 8
#define LL0 128
#define LL1 256

// 2 * log2(e): pre-scale factor so tanh(t) can use v_exp_f32 (2^x) directly.
#define LOG2E2 2.8853900817779268f

// split-K partial plane stride (floats): 3072 rows x 512 e
#define PSTR ((size_t)3072 * 512)

__device__ __forceinline__ float fexp2(float x) {
#if __has_builtin(__builtin_amdgcn_exp2f)
    return __builtin_amdgcn_exp2f(x);
#else
    float r; asm("v_exp_f32 %0, %1" : "=v"(r) : "v"(x)); return r;
#endif
}
__device__ __forceinline__ float frcp(float x) {
#if __has_builtin(__builtin_amdgcn_rcpf)
    return __builtin_amdgcn_rcpf(x);
#else
    float r; asm("v_rcp_f32 %0, %1" : "=v"(r) : "v"(x)); return r;
#endif
}

// sigma2(t2) = 1/(2^t2 + 1), where t2 = 2*log2e*t.  tanh(t) = 1 - 2*sigma2.
__device__ __forceinline__ float sig2(float t2) {
    return frcp(fexp2(t2) + 1.0f);
}

// ---------------------------------------------------------------------------
// Kernel 0: mask compaction (one block per n).
// bidx[n][j] = j-th valid b (padded with 0), jinv[n][b] = j or -1, cnt[n].
// ---------------------------------------------------------------------------
__global__ __launch_bounds__(256) void compact_kernel(
    const int* __restrict__ mask, int* __restrict__ bidx,
    int* __restrict__ jinv, int* __restrict__ cnt)
{
    __shared__ int wsum[4];
    int n = blockIdx.x, b = threadIdx.x;
    int v = (mask[n * LL1 + b] != 0) ? 1 : 0;
    unsigned long long bal = __ballot(v);
    int lane = b & 63, wv = b >> 6;
    int wpre = __popcll(bal & ((1ull << lane) - 1ull));
    if (lane == 63) wsum[wv] = wpre + v;     // wave total
    bidx[n * LL1 + b] = 0;                   // padding default
    __syncthreads();
    int base = 0;
    #pragma unroll
    for (int i = 0; i < 4; ++i) base += (i < wv) ? wsum[i] : 0;
    int pos = base + wpre;
    if (v) {
        bidx[n * LL1 + pos] = b;
        jinv[n * LL1 + b] = pos;
    } else {
        jinv[n * LL1 + b] = -1;
    }
    if (b == 255) cnt[n] = pos + v;          // total valid count
}

// ---------------------------------------------------------------------------
// Kernel 1: fused projections. 128(rows) x 64(e) tile, 8x4 micro-tile,
// split-K=4 (K-chunk 128 per block, 4 K-tiles of 32).
// Double-buffered LDS, ONE barrier per K-tile.
// LDS/FMA = 1.5 B (3x ds_read_b128 per 32 FMAs: a-frags are 4-address
// broadcast reads, b-frag is 2-way-free). LDS 51.2 KB -> 3 blocks/CU.
// Grid (24, 8, 4) = 768 blocks = 3.0/CU exact.
// ---------------------------------------------------------------------------
__global__ __launch_bounds__(256, 3) void proj_kernel(
    const float* __restrict__ x, const float* __restrict__ m,
    const float* __restrict__ W, float* __restrict__ pp)
{
    __shared__ float At[2][32][132];   // [buf][k][row], 132*4 B row stride
    __shared__ float Bt[2][32][68];    // [buf][k][e]

    int row0 = blockIdx.x * 128;
    int e0   = blockIdx.y * 64;
    int kb   = blockIdx.z * 128;       // K-quarter base

    bool isx = row0 < (NN * LL0);
    const float* A  = (isx ? x + (size_t)row0 * DD
                           : m + (size_t)(row0 - NN * LL0) * DD) + kb;
    const float* Wp = W + (size_t)e0 * (2 * DD) + (isx ? 0 : DD) + kb;

    int t  = threadIdx.x;
    int ar = t >> 1, ac = (t & 1) * 16;   // A staging: row 0..127, k-off 0/16
    int br = t >> 2, bc = (t & 3) * 8;    // B staging: e 0..63, k-off 0,8,16,24
    int ty = t >> 4, tx = t & 15;         // micro: rows {ty*4+i, 64+ty*4+i}, cols tx*4..+3

    const float* Ap = A  + (size_t)ar * DD + ac;
    const float* Bp = Wp + (size_t)br * (2 * DD) + bc;

    float4 a0 = *(const float4*)(Ap);
    float4 a1 = *(const float4*)(Ap + 4);
    float4 a2 = *(const float4*)(Ap + 8);
    float4 a3 = *(const float4*)(Ap + 12);
    float4 b0 = *(const float4*)(Bp);
    float4 b1 = *(const float4*)(Bp + 4);

    // tile 0 -> buf 0 (transposed [k][row]; conflict-free: lanes differ in ar/br)
    At[0][ac + 0][ar] = a0.x;  At[0][ac + 1][ar] = a0.y;
    At[0][ac + 2][ar] = a0.z;  At[0][ac + 3][ar] = a0.w;
    At[0][ac + 4][ar] = a1.x;  At[0][ac + 5][ar] = a1.y;
    At[0][ac + 6][ar] = a1.z;  At[0][ac + 7][ar] = a1.w;
    At[0][ac + 8][ar] = a2.x;  At[0][ac + 9][ar] = a2.y;
    At[0][ac + 10][ar] = a2.z; At[0][ac + 11][ar] = a2.w;
    At[0][ac + 12][ar] = a3.x; At[0][ac + 13][ar] = a3.y;
    At[0][ac + 14][ar] = a3.z; At[0][ac + 15][ar] = a3.w;
    Bt[0][bc + 0][br] = b0.x;  Bt[0][bc + 1][br] = b0.y;
    Bt[0][bc + 2][br] = b0.z;  Bt[0][bc + 3][br] = b0.w;
    Bt[0][bc + 4][br] = b1.x;  Bt[0][bc + 5][br] = b1.y;
    Bt[0][bc + 6][br] = b1.z;  Bt[0][bc + 7][br] = b1.w;
    __syncthreads();

    float acc[8][4] = {};

    #pragma unroll 1
    for (int kt = 0; kt < 4; ++kt) {
        int cur = kt & 1;
        if (kt < 3) {   // prefetch next K-tile into registers (hides latency)
            int ko = (kt + 1) * 32;
            a0 = *(const float4*)(Ap + ko);
            a1 = *(const float4*)(Ap + ko + 4);
            a2 = *(const float4*)(Ap + ko + 8);
            a3 = *(const float4*)(Ap + ko + 12);
            b0 = *(const float4*)(Bp + ko);
            b1 = *(const float4*)(Bp + ko + 4);
        }
        #pragma unroll 4
        for (int kk = 0; kk < 32; ++kk) {
            float4 av0 = *(const float4*)&At[cur][kk][ty * 4];
            float4 av1 = *(const float4*)&At[cur][kk][64 + ty * 4];
            float4 bv  = *(const float4*)&Bt[cur][kk][tx * 4];
            float a_[8] = {av0.x, av0.y, av0.z, av0.w,
                           av1.x, av1.y, av1.z, av1.w};
            #pragma unroll
            for (int i = 0; i < 8; ++i) {
                acc[i][0] = fmaf(a_[i], bv.x, acc[i][0]);
                acc[i][1] = fmaf(a_[i], bv.y, acc[i][1]);
                acc[i][2] = fmaf(a_[i], bv.z, acc[i][2]);
                acc[i][3] = fmaf(a_[i], bv.w, acc[i][3]);
            }
        }
        if (kt < 3) {
            int nxt = cur ^ 1;
            At[nxt][ac + 0][ar] = a0.x;  At[nxt][ac + 1][ar] = a0.y;
            At[nxt][ac + 2][ar] = a0.z;  At[nxt][ac + 3][ar] = a0.w;
            At[nxt][ac + 4][ar] = a1.x;  At[nxt][ac + 5][ar] = a1.y;
            At[nxt][ac + 6][ar] = a1.z;  At[nxt][ac + 7][ar] = a1.w;
            At[nxt][ac + 8][ar] = a2.x;  At[nxt][ac + 9][ar] = a2.y;
            At[nxt][ac + 10][ar] = a2.z; At[nxt][ac + 11][ar] = a2.w;
            At[nxt][ac + 12][ar] = a3.x; At[nxt][ac + 13][ar] = a3.y;
            At[nxt][ac + 14][ar] = a3.z; At[nxt][ac + 15][ar] = a3.w;
            Bt[nxt][bc + 0][br] = b0.x;  Bt[nxt][bc + 1][br] = b0.y;
            Bt[nxt][bc + 2][br] = b0.z;  Bt[nxt][bc + 3][br] = b0.w;
            Bt[nxt][bc + 4][br] = b1.x;  Bt[nxt][bc + 5][br] = b1.y;
            Bt[nxt][bc + 6][br] = b1.z;  Bt[nxt][bc + 7][br] = b1.w;
            __syncthreads();
        }
    }

    float* outp = pp + (size_t)blockIdx.z * PSTR
                     + (size_t)row0 * DD + e0 + tx * 4;
    #pragma unroll
    for (int i = 0; i < 4; ++i) {
        *(float4*)(outp + (size_t)(ty * 4 + i) * DD) =
            make_float4(acc[i][0], acc[i][1], acc[i][2], acc[i][3]);
        *(float4*)(outp + (size_t)(64 + ty * 4 + i) * DD) =
            make_float4(acc[4 + i][0], acc[4 + i][1], acc[4 + i][2], acc[4 + i][3]);
    }
}

// ---------------------------------------------------------------------------
// Kernel 1b: split-K reduce (4 planes) + bias + LOG2E2 scale.
// ---------------------------------------------------------------------------
__global__ __launch_bounds__(256) void reduce_kernel(
    const float* __restrict__ pp, const float* __restrict__ Wb,
    float* __restrict__ xpb_base)
{
    size_t f = (size_t)blockIdx.x * 256 + threadIdx.x;   // float4 index
    const float4* p4 = (const float4*)pp;
    float4 v0 = p4[f];
    float4 v1 = p4[f + PSTR / 4];
    float4 v2 = p4[f + 2 * (PSTR / 4)];
    float4 v3 = p4[f + 3 * (PSTR / 4)];
    float4 s = make_float4(v0.x + v1.x + v2.x + v3.x,
                           v0.y + v1.y + v2.y + v3.y,
                           v0.z + v1.z + v2.z + v3.z,
                           v0.w + v1.w + v2.w + v3.w);
    size_t off = f * 4;
    if (off < (size_t)NN * LL0 * DD) {   // x-rows: add bias
        float4 wb = *(const float4*)(Wb + (off & (DD - 1)));
        s.x += wb.x; s.y += wb.y; s.z += wb.z; s.w += wb.w;
    }
    s.x *= LOG2E2; s.y *= LOG2E2; s.z *= LOG2E2; s.w *= LOG2E2;
    ((float4*)xpb_base)[f] = s;
}

// ---------------------------------------------------------------------------
// Kernel 2: logits on COMPACTED b only.  (launch_bounds relaxed to 4: 64 VGPR,
// no spill risk from the gather address arithmetic.)
//   wpart[dc][n][a][j] = sum_{d in chunk dc} V[d]/(2^(xp[n,a,d]+mp[n,bidx[j],d])+1)
// ---------------------------------------------------------------------------
__global__ __launch_bounds__(256, 4) void logits_kernel(
    const float* __restrict__ xpb, const float* __restrict__ mp,
    const float* __restrict__ Vw, const int* __restrict__ bidx,
    const int* __restrict__ cnt, float* __restrict__ wpart)
{
    __shared__ __attribute__((aligned(16))) float xs[32][68];
    __shared__ __attribute__((aligned(16))) float ms[32][68];
    __shared__ __attribute__((aligned(16))) float vsh[64];

    int n  = blockIdx.z;
    int bt = blockIdx.x;          // compact j-tile of 32
    int at = blockIdx.y & 3;      // 0..3 (32 a-rows)
    int dc = blockIdx.y >> 2;     // 0..7 (64 d)
    int jbase = bt * 32;
    if (jbase >= cnt[n]) return;  // tile fully beyond valid count

    int tid = threadIdx.x;
    int ty = tid >> 4, tx = tid & 15;

    const float* xrow = xpb + (size_t)(n * LL0 + at * 32) * DD + dc * 64;

    {
        int r  = tid >> 3;            // 0..31
        int c8 = (tid & 7) * 8;       // 0..56
        *(float4*)&xs[r][c8]     = *(const float4*)(xrow + (size_t)r * DD + c8);
        *(float4*)&xs[r][c8 + 4] = *(const float4*)(xrow + (size_t)r * DD + c8 + 4);
        int bj = bidx[n * LL1 + jbase + r];          // gather index (pad -> 0)
        const float* mrow = mp + ((size_t)n * LL1 + bj) * DD + dc * 64;
        *(float4*)&ms[r][c8]     = *(const float4*)(mrow + c8);
        *(float4*)&ms[r][c8 + 4] = *(const float4*)(mrow + c8 + 4);
        if (tid < 16)
            *(float4*)&vsh[tid * 4] = *(const float4*)(Vw + dc * 64 + tid * 4);
    }
    __syncthreads();

    float a00 = 0.f, a01 = 0.f, a10 = 0.f, a11 = 0.f;

    #pragma unroll 4
    for (int k4 = 0; k4 < 16; ++k4) {
        float4 xa = *(const float4*)&xs[ty][k4 * 4];
        float4 xb = *(const float4*)&xs[ty + 16][k4 * 4];
        float4 ma = *(const float4*)&ms[tx][k4 * 4];
        float4 mb = *(const float4*)&ms[tx + 16][k4 * 4];
        float4 vv = *(const float4*)&vsh[k4 * 4];

        a00 = fmaf(vv.x, sig2(xa.x + ma.x), a00);
        a00 = fmaf(vv.y, sig2(xa.y + ma.y), a00);
        a00 = fmaf(vv.z, sig2(xa.z + ma.z), a00);
        a00 = fmaf(vv.w, sig2(xa.w + ma.w), a00);

        a01 = fmaf(vv.x, sig2(xa.x + mb.x), a01);
        a01 = fmaf(vv.y, sig2(xa.y + mb.y), a01);
        a01 = fmaf(vv.z, sig2(xa.z + mb.z), a01);
        a01 = fmaf(vv.w, sig2(xa.w + mb.w), a01);

        a10 = fmaf(vv.x, sig2(xb.x + ma.x), a10);
        a10 = fmaf(vv.y, sig2(xb.y + ma.y), a10);
        a10 = fmaf(vv.z, sig2(xb.z + ma.z), a10);
        a10 = fmaf(vv.w, sig2(xb.w + ma.w), a10);

        a11 = fmaf(vv.x, sig2(xb.x + mb.x), a11);
        a11 = fmaf(vv.y, sig2(xb.y + mb.y), a11);
        a11 = fmaf(vv.z, sig2(xb.z + mb.z), a11);
        a11 = fmaf(vv.w, sig2(xb.w + mb.w), a11);
    }

    const size_t P = (size_t)NN * LL0 * LL1;
    float* wp = wpart + (size_t)dc * P + ((size_t)n * LL0 + at * 32) * LL1;
    wp[(size_t)ty * LL1 + jbase + tx]             = a00;
    wp[(size_t)ty * LL1 + jbase + tx + 16]        = a01;
    wp[(size_t)(ty + 16) * LL1 + jbase + tx]      = a10;
    wp[(size_t)(ty + 16) * LL1 + jbase + tx + 16] = a11;
}

// ---------------------------------------------------------------------------
// Kernel 3: masked softmax. Gathers the 8 compact-plane partials via jinv,
// applies -2 scale, softmax over valid b (masked -> exactly 0), writes the
// DENSE result into plane 0 of wpart (consumed by vgemm).
// ---------------------------------------------------------------------------
__global__ __launch_bounds__(256) void softmax_kernel(
    float* __restrict__ wpart, const int* __restrict__ jinv)
{
    __shared__ float red[4];
    __shared__ float red2[4];
    const size_t P = (size_t)NN * LL0 * LL1;
    int row = blockIdx.x;          // n*L0 + a
    int n = row >> 7;
    int b = threadIdx.x;
    size_t rowoff = (size_t)row * LL1;

    int j = jinv[n * LL1 + b];
    float w = -1e30f;
    if (j >= 0) {
        float s8 = 0.f;
        #pragma unroll
        for (int p = 0; p < 8; ++p) s8 += wpart[(size_t)p * P + rowoff + j];
        w = -2.0f * s8;
    }

    float mx = w;
    #pragma unroll
    for (int off = 32; off; off >>= 1) mx = fmaxf(mx, __shfl_xor(mx, off));
    int wv = threadIdx.x >> 6;
    if ((threadIdx.x & 63) == 0) red[wv] = mx;
    __syncthreads();
    mx = fmaxf(fmaxf(red[0], red[1]), fmaxf(red[2], red[3]));

    float e = (j >= 0) ? __expf(w - mx) : 0.f;
    float s = e;
    #pragma unroll
    for (int off = 32; off; off >>= 1) s += __shfl_xor(s, off);
    if ((threadIdx.x & 63) == 0) red2[wv] = s;
    __syncthreads();
    s = red2[0] + red2[1] + red2[2] + red2[3];

    wpart[rowoff + b] = e / s;     // dense write into plane 0 (reads done first)
}

// ---------------------------------------------------------------------------
// Kernel 4: v[n,a,d] = sum_b w[n,a,b] * m[n,b,d]. (unchanged; masked w == 0)
// ---------------------------------------------------------------------------
__global__ __launch_bounds__(256) void vgemm_kernel(
    const float* __restrict__ wbuf, const float* __restrict__ m,
    float* __restrict__ out)
{
    __shared__ float ws_t[64][17];
    __shared__ float ms_t[16][65];

    int n = blockIdx.z;
    int a0 = blockIdx.y * 64;
    int d0 = blockIdx.x * 64;
    int tid = threadIdx.x;
    int ty = tid >> 4, tx = tid & 15;

    const float* wrow = wbuf + ((size_t)n * LL0 + a0) * LL1;
    const float* mrow = m + (size_t)n * LL1 * DD;

    float acc[4][4] = {};
    for (int k0 = 0; k0 < LL1; k0 += 16) {
        {
            int lr = tid >> 2, lc = (tid & 3) * 4;
            float4 wv = *(const float4*)(wrow + (size_t)lr * LL1 + k0 + lc);
            ws_t[lr][lc + 0] = wv.x; ws_t[lr][lc + 1] = wv.y;
            ws_t[lr][lc + 2] = wv.z; ws_t[lr][lc + 3] = wv.w;
        }
        {
            int lr = tid >> 4, lc = (tid & 15) * 4;
            float4 mv = *(const float4*)(mrow + (size_t)(k0 + lr) * DD + d0 + lc);
            ms_t[lr][lc + 0] = mv.x; ms_t[lr][lc + 1] = mv.y;
            ms_t[lr][lc + 2] = mv.z; ms_t[lr][lc + 3] = mv.w;
        }
        __syncthreads();
        #pragma unroll
        for (int kk = 0; kk < 16; ++kk) {
            float a_[4], b_[4];
            #pragma unroll
            for (int i = 0; i < 4; ++i) a_[i] = ws_t[ty * 4 + i][kk];
            #pragma unroll
            for (int j = 0; j < 4; ++j) b_[j] = ms_t[kk][tx * 4 + j];
            #pragma unroll
            for (int i = 0; i < 4; ++i)
                #pragma unroll
                for (int j = 0; j < 4; ++j)
                    acc[i][j] = fmaf(a_[i], b_[j], acc[i][j]);
        }
        __syncthreads();
    }
    #pragma unroll
    for (int i = 0; i < 4; ++i)
        #pragma unroll
        for (int j = 0; j < 4; ++j)
            out[((size_t)n * LL0 + a0 + ty * 4 + i) * DD + d0 + tx * 4 + j] = acc[i][j];
}

extern "C" void kernel_launch(void* const* d_in, const int* in_sizes, int n_in,
                              void* d_out, int out_size, void* d_ws, size_t ws_size,
                              hipStream_t stream) {
    const float* x    = (const float*)d_in[0];
    const float* m    = (const float*)d_in[1];
    const int*   mask = (const int*)d_in[2];
    const float* W_w  = (const float*)d_in[3];
    const float* W_b  = (const float*)d_in[4];
    const float* V_w  = (const float*)d_in[5];
    const float* V_b  = (const float*)d_in[6];
    (void)V_b; // additive constant — cancels under softmax shift-invariance
    float* out = (float*)d_out;

    // Workspace layout (floats):
    //   xpb    : 8*128*512            =  524288
    //   mp     : 8*256*512            = 1048576   (contiguous after xpb)
    //   region : max(pp 4*3072*512 = 6291456, wpart 8*8*128*256 = 2097152)
    //   ints   : bidx 2048 + jinv 2048 + cnt 8    (after region's 4*PSTR)
    // Total: ~31.5 MB + 16 KB
    float* xpb    = (float*)d_ws;
    float* mp     = xpb + (size_t)NN * LL0 * DD;
    float* region = mp + (size_t)NN * LL1 * DD;
    float* pp     = region;
    float* wpart  = region;
    int*   bidx   = (int*)(region + 4 * PSTR);
    int*   jinv   = bidx + NN * LL1;
    int*   cnt    = jinv + NN * LL1;

    compact_kernel<<<dim3(8), 256, 0, stream>>>(mask, bidx, jinv, cnt);
    proj_kernel<<<dim3(24, 8, 4), 256, 0, stream>>>(x, m, W_w, pp);
    reduce_kernel<<<dim3(1536), 256, 0, stream>>>(pp, W_b, xpb);
    logits_kernel<<<dim3(8, 32, 8), 256, 0, stream>>>(xpb, mp, V_w, bidx, cnt, wpart);
    softmax_kernel<<<dim3(1024), 256, 0, stream>>>(wpart, jinv);
    vgemm_kernel<<<dim3(8, 2, 8), 256, 0, stream>>>(wpart, m, out);
}

// Round 8
// 74.512 us; speedup vs baseline: 1.2262x; 1.2047x over previous
//
#include <hip/hip_runtime.h>
#include <hip/hip_bf16.h>

#define DD 512
#define NN 8
#define LL0 128
#define LL1 256

// 2 * log2(e): pre-scale so tanh(t) needs only v_exp_f32 (2^x).
#define LOG2E2 2.8853900817779268f

// split-K partial plane stride (floats): 3072 rows x 512 e
#define PSTR ((size_t)3072 * 512)

__device__ __forceinline__ float fexp2(float x) {
#if __has_builtin(__builtin_amdgcn_exp2f)
    return __builtin_amdgcn_exp2f(x);
#else
    float r; asm("v_exp_f32 %0, %1" : "=v"(r) : "v"(x)); return r;
#endif
}
__device__ __forceinline__ float frcp(float x) {
#if __has_builtin(__builtin_amdgcn_rcpf)
    return __builtin_amdgcn_rcpf(x);
#else
    float r; asm("v_rcp_f32 %0, %1" : "=v"(r) : "v"(x)); return r;
#endif
}

// sigma2(t2) = 1/(2^t2 + 1); tanh(t) = 1 - 2*sigma2(2*log2e*t).
__device__ __forceinline__ float sig2(float t2) {
    return frcp(fexp2(t2) + 1.0f);
}

// ---------------------------------------------------------------------------
// Kernel 1: fused projections, split-K=2 (round-2 exact, best-measured).
// pp[kz][row][e] = sum_{k in half kz} A[row,k] * W[e, koff+k]
// Tile 64(M) x 64(e), K-chunk 32, 4x4 micro-tile; LDS transposed [k][row].
// Grid (48, 8, 2) = 768 blocks = 3.0/CU exact.
// ---------------------------------------------------------------------------
__global__ __launch_bounds__(256, 3) void proj_kernel(
    const float* __restrict__ x, const float* __restrict__ m,
    const float* __restrict__ W, float* __restrict__ pp)
{
    __shared__ float At[32][68];
    __shared__ float Bt[32][68];

    int row0 = blockIdx.x * 64;
    int e0   = blockIdx.y * 64;
    int kb   = blockIdx.z * 256;   // K-half base

    bool isx = row0 < (NN * LL0);
    const float* A  = (isx ? x + (size_t)row0 * DD
                           : m + (size_t)(row0 - NN * LL0) * DD) + kb;
    const float* Wp = W + (size_t)e0 * (2 * DD) + (isx ? 0 : DD) + kb;

    int t  = threadIdx.x;
    int lr = t >> 2;              // 0..63
    int kc = (t & 3) * 8;         // 0,8,16,24
    int ty = t >> 4, tx = t & 15;

    const float* Ap = A  + (size_t)lr * DD + kc;
    const float* Bp = Wp + (size_t)lr * (2 * DD) + kc;

    float4 ar0 = *(const float4*)(Ap);
    float4 ar1 = *(const float4*)(Ap + 4);
    float4 br0 = *(const float4*)(Bp);
    float4 br1 = *(const float4*)(Bp + 4);

    float acc[4][4] = {};

    for (int kt = 0; kt < 8; ++kt) {
        if (kt) __syncthreads();
        At[kc + 0][lr] = ar0.x; At[kc + 1][lr] = ar0.y;
        At[kc + 2][lr] = ar0.z; At[kc + 3][lr] = ar0.w;
        At[kc + 4][lr] = ar1.x; At[kc + 5][lr] = ar1.y;
        At[kc + 6][lr] = ar1.z; At[kc + 7][lr] = ar1.w;
        Bt[kc + 0][lr] = br0.x; Bt[kc + 1][lr] = br0.y;
        Bt[kc + 2][lr] = br0.z; Bt[kc + 3][lr] = br0.w;
        Bt[kc + 4][lr] = br1.x; Bt[kc + 5][lr] = br1.y;
        Bt[kc + 6][lr] = br1.z; Bt[kc + 7][lr] = br1.w;
        if (kt < 7) {
            int ko = (kt + 1) * 32;
            ar0 = *(const float4*)(Ap + ko);
            ar1 = *(const float4*)(Ap + ko + 4);
            br0 = *(const float4*)(Bp + ko);
            br1 = *(const float4*)(Bp + ko + 4);
        }
        __syncthreads();

        #pragma unroll
        for (int kk = 0; kk < 32; ++kk) {
            float4 av = *(const float4*)&At[kk][ty * 4];
            float4 bv = *(const float4*)&Bt[kk][tx * 4];
            acc[0][0] = fmaf(av.x, bv.x, acc[0][0]);
            acc[0][1] = fmaf(av.x, bv.y, acc[0][1]);
            acc[0][2] = fmaf(av.x, bv.z, acc[0][2]);
            acc[0][3] = fmaf(av.x, bv.w, acc[0][3]);
            acc[1][0] = fmaf(av.y, bv.x, acc[1][0]);
            acc[1][1] = fmaf(av.y, bv.y, acc[1][1]);
            acc[1][2] = fmaf(av.y, bv.z, acc[1][2]);
            acc[1][3] = fmaf(av.y, bv.w, acc[1][3]);
            acc[2][0] = fmaf(av.z, bv.x, acc[2][0]);
            acc[2][1] = fmaf(av.z, bv.y, acc[2][1]);
            acc[2][2] = fmaf(av.z, bv.z, acc[2][2]);
            acc[2][3] = fmaf(av.z, bv.w, acc[2][3]);
            acc[3][0] = fmaf(av.w, bv.x, acc[3][0]);
            acc[3][1] = fmaf(av.w, bv.y, acc[3][1]);
            acc[3][2] = fmaf(av.w, bv.z, acc[3][2]);
            acc[3][3] = fmaf(av.w, bv.w, acc[3][3]);
        }
    }

    float* outp = pp + (size_t)blockIdx.z * PSTR
                     + (size_t)row0 * DD + e0 + tx * 4;
    #pragma unroll
    for (int i = 0; i < 4; ++i) {
        float4 v = make_float4(acc[i][0], acc[i][1], acc[i][2], acc[i][3]);
        *(float4*)(outp + (size_t)(ty * 4 + i) * DD) = v;
    }
}

// ---------------------------------------------------------------------------
// Kernel 2: logits with FUSED split-K reduce + bias + scale during staging.
//   xs[d][a] = LOG2E2*(pp0 + pp1 + Wb)   (x-proj rows)
//   ms[d][b] = LOG2E2*(pp0 + pp1)        (m-proj rows)
//   wpart[dc][n][a][b] = sum_{d in chunk} V[d] * sig2(xs + ms)
// Tile 32a x 64b x 64d, 2a x 4b micro-tile (8 indep sig2 chains per kk).
// FIX vs round 7: ms second dim 36 -> 68 (b spans 64; was out-of-bounds).
// Grid (4, 32, 8) = 1024 blocks = 4.0/CU; LDS 26.4 KB.
// ---------------------------------------------------------------------------
__global__ __launch_bounds__(256, 4) void logits_kernel(
    const float* __restrict__ pp, const float* __restrict__ Wb,
    const float* __restrict__ Vw, float* __restrict__ wpart)
{
    __shared__ __attribute__((aligned(16))) float xs[64][34];  // [d][a: 32+2]
    __shared__ __attribute__((aligned(16))) float ms[64][68];  // [d][b: 64+4]
    __shared__ __attribute__((aligned(16))) float vsh[64];

    int n  = blockIdx.z;
    int bt = blockIdx.x;          // 0..3 : 64 b-cols
    int at = blockIdx.y & 3;      // 0..3 : 32 a-rows
    int dc = blockIdx.y >> 2;     // 0..7 : 64-d chunk
    int tid = threadIdx.x;
    int ty = tid >> 4, tx = tid & 15;

    // ---- stage x-part: 32 rows x 64 d, summing 2 planes, + bias, * scale
    {
        int r  = tid & 31;            // lane-major row -> conflict-free LDS writes
        int c8 = (tid >> 5) * 8;      // 0..56
        size_t base = ((size_t)(n * LL0 + at * 32) + r) * DD + dc * 64 + c8;
        float4 p00 = *(const float4*)(pp + base);
        float4 p01 = *(const float4*)(pp + base + 4);
        float4 p10 = *(const float4*)(pp + PSTR + base);
        float4 p11 = *(const float4*)(pp + PSTR + base + 4);
        float4 w0  = *(const float4*)(Wb + dc * 64 + c8);
        float4 w1  = *(const float4*)(Wb + dc * 64 + c8 + 4);
        xs[c8 + 0][r] = LOG2E2 * (p00.x + p10.x + w0.x);
        xs[c8 + 1][r] = LOG2E2 * (p00.y + p10.y + w0.y);
        xs[c8 + 2][r] = LOG2E2 * (p00.z + p10.z + w0.z);
        xs[c8 + 3][r] = LOG2E2 * (p00.w + p10.w + w0.w);
        xs[c8 + 4][r] = LOG2E2 * (p01.x + p11.x + w1.x);
        xs[c8 + 5][r] = LOG2E2 * (p01.y + p11.y + w1.y);
        xs[c8 + 6][r] = LOG2E2 * (p01.z + p11.z + w1.z);
        xs[c8 + 7][r] = LOG2E2 * (p01.w + p11.w + w1.w);
    }
    // ---- stage m-part: 64 rows x 64 d (rows live at pp offset 1024 + n*256)
    {
        int r   = tid & 63;           // lane-major row
        int c16 = (tid >> 6) * 16;    // 0,16,32,48
        size_t base = ((size_t)(NN * LL0 + n * LL1 + bt * 64) + r) * DD
                      + dc * 64 + c16;
        #pragma unroll
        for (int q = 0; q < 4; ++q) {
            float4 p0 = *(const float4*)(pp + base + q * 4);
            float4 p1 = *(const float4*)(pp + PSTR + base + q * 4);
            int c = c16 + q * 4;
            ms[c + 0][r] = LOG2E2 * (p0.x + p1.x);
            ms[c + 1][r] = LOG2E2 * (p0.y + p1.y);
            ms[c + 2][r] = LOG2E2 * (p0.z + p1.z);
            ms[c + 3][r] = LOG2E2 * (p0.w + p1.w);
        }
        if (tid < 16)
            *(float4*)&vsh[tid * 4] = *(const float4*)(Vw + dc * 64 + tid * 4);
    }
    __syncthreads();

    float acc[2][4] = {};

    #pragma unroll 8
    for (int kk = 0; kk < 64; ++kk) {
        float2 xa = *(const float2*)&xs[kk][ty * 2];   // 2 a-values (b64)
        float4 mb = *(const float4*)&ms[kk][tx * 4];   // 4 b-values (b128)
        float  vv = vsh[kk];
        float b_[4] = {mb.x, mb.y, mb.z, mb.w};
        #pragma unroll
        for (int j = 0; j < 4; ++j) {
            acc[0][j] = fmaf(vv, sig2(xa.x + b_[j]), acc[0][j]);
            acc[1][j] = fmaf(vv, sig2(xa.y + b_[j]), acc[1][j]);
        }
    }

    const size_t P = (size_t)NN * LL0 * LL1;
    float* wp = wpart + (size_t)dc * P
              + ((size_t)n * LL0 + at * 32 + ty * 2) * LL1 + bt * 64 + tx * 4;
    *(float4*)(wp)       = make_float4(acc[0][0], acc[0][1], acc[0][2], acc[0][3]);
    *(float4*)(wp + LL1) = make_float4(acc[1][0], acc[1][1], acc[1][2], acc[1][3]);
}

// ---------------------------------------------------------------------------
// Kernel 3: masked softmax over b (sums 8 d-chunk partials, -2 scale).
// Writes dense result into plane 0 of wpart.
// ---------------------------------------------------------------------------
__global__ __launch_bounds__(256) void softmax_kernel(
    float* __restrict__ wpart, const int* __restrict__ mask)
{
    __shared__ float red[4];
    __shared__ float red2[4];
    const size_t P = (size_t)NN * LL0 * LL1;
    int row = blockIdx.x;          // n*L0 + a
    int n = row >> 7;
    int b = threadIdx.x;
    size_t idx = (size_t)row * LL1 + b;

    float s8 = 0.f;
    #pragma unroll
    for (int p = 0; p < 8; ++p) s8 += wpart[idx + (size_t)p * P];
    float w = -2.0f * s8;
    if (mask[n * LL1 + b] == 0) w = -1e30f;

    float mx = w;
    #pragma unroll
    for (int off = 32; off; off >>= 1) mx = fmaxf(mx, __shfl_xor(mx, off));
    int wv = threadIdx.x >> 6;
    if ((threadIdx.x & 63) == 0) red[wv] = mx;
    __syncthreads();
    mx = fmaxf(fmaxf(red[0], red[1]), fmaxf(red[2], red[3]));

    float e = (w > -1e29f) ? __expf(w - mx) : 0.f;
    float s = e;
    #pragma unroll
    for (int off = 32; off; off >>= 1) s += __shfl_xor(s, off);
    if ((threadIdx.x & 63) == 0) red2[wv] = s;
    __syncthreads();
    s = red2[0] + red2[1] + red2[2] + red2[3];

    wpart[idx] = e / s;            // dense write into plane 0 (reads done first)
}

// ---------------------------------------------------------------------------
// Kernel 4: v[n,a,d] = sum_b w[n,a,b] * m[n,b,d].
// Tile 32a x 64d, K-chunk 32, 2a x 4d micro-tile; w transposed [k][a] in LDS.
// Grid (8, 4, 8) = 256 blocks = 1.0/CU exact.
// ---------------------------------------------------------------------------
__global__ __launch_bounds__(256, 4) void vgemm_kernel(
    const float* __restrict__ wbuf, const float* __restrict__ m,
    float* __restrict__ out)
{
    __shared__ float wt[32][36];   // [k][a: 32+4]
    __shared__ float mt[32][68];   // [k][d: 64+4]

    int n  = blockIdx.z;
    int a0 = blockIdx.y * 32;
    int d0 = blockIdx.x * 64;
    int tid = threadIdx.x;
    int ty = tid >> 4, tx = tid & 15;

    const float* wrow = wbuf + ((size_t)n * LL0 + a0) * LL1;
    const float* mrow = m + (size_t)n * LL1 * DD;

    float acc[2][4] = {};
    for (int k0 = 0; k0 < LL1; k0 += 32) {
        {
            int r  = tid >> 3;            // a-row 0..31
            int c4 = (tid & 7) * 4;       // k 0..28
            float4 wv = *(const float4*)(wrow + (size_t)r * LL1 + k0 + c4);
            wt[c4 + 0][r] = wv.x; wt[c4 + 1][r] = wv.y;
            wt[c4 + 2][r] = wv.z; wt[c4 + 3][r] = wv.w;
        }
        {
            int r  = tid >> 3;            // k-row 0..31
            int c8 = (tid & 7) * 8;       // d 0..56
            const float* src = mrow + (size_t)(k0 + r) * DD + d0 + c8;
            *(float4*)&mt[r][c8]     = *(const float4*)(src);
            *(float4*)&mt[r][c8 + 4] = *(const float4*)(src + 4);
        }
        __syncthreads();
        #pragma unroll 8
        for (int kk = 0; kk < 32; ++kk) {
            float2 av = *(const float2*)&wt[kk][ty * 2];
            float4 bv = *(const float4*)&mt[kk][tx * 4];
            acc[0][0] = fmaf(av.x, bv.x, acc[0][0]);
            acc[0][1] = fmaf(av.x, bv.y, acc[0][1]);
            acc[0][2] = fmaf(av.x, bv.z, acc[0][2]);
            acc[0][3] = fmaf(av.x, bv.w, acc[0][3]);
            acc[1][0] = fmaf(av.y, bv.x, acc[1][0]);
            acc[1][1] = fmaf(av.y, bv.y, acc[1][1]);
            acc[1][2] = fmaf(av.y, bv.z, acc[1][2]);
            acc[1][3] = fmaf(av.y, bv.w, acc[1][3]);
        }
        __syncthreads();
    }
    float* op = out + ((size_t)n * LL0 + a0 + ty * 2) * DD + d0 + tx * 4;
    *(float4*)(op)      = make_float4(acc[0][0], acc[0][1], acc[0][2], acc[0][3]);
    *(float4*)(op + DD) = make_float4(acc[1][0], acc[1][1], acc[1][2], acc[1][3]);
}

extern "C" void kernel_launch(void* const* d_in, const int* in_sizes, int n_in,
                              void* d_out, int out_size, void* d_ws, size_t ws_size,
                              hipStream_t stream) {
    const float* x    = (const float*)d_in[0];
    const float* m    = (const float*)d_in[1];
    const int*   mask = (const int*)d_in[2];
    const float* W_w  = (const float*)d_in[3];
    const float* W_b  = (const float*)d_in[4];
    const float* V_w  = (const float*)d_in[5];
    const float* V_b  = (const float*)d_in[6];
    (void)V_b; // additive constant — cancels under softmax shift-invariance
    float* out = (float*)d_out;

    // Workspace (floats):
    //   pp    : 2 * PSTR = 3,145,728   (split-K projection partials)
    //   wpart : 8 * 8*128*256 = 2,097,152  (logit partials; plane 0 reused as w)
    // Total: 5,242,880 floats = 21.0 MB
    float* pp    = (float*)d_ws;
    float* wpart = pp + 2 * PSTR;

    proj_kernel<<<dim3(48, 8, 2), 256, 0, stream>>>(x, m, W_w, pp);
    logits_kernel<<<dim3(4, 32, 8), 256, 0, stream>>>(pp, W_b, V_w, wpart);
    softmax_kernel<<<dim3(1024), 256, 0, stream>>>(wpart, mask);
    vgemm_kernel<<<dim3(8, 4, 8), 256, 0, stream>>>(wpart, m, out);
}

// Round 9
// 62.109 us; speedup vs baseline: 1.4711x; 1.1997x over previous
//
#include <hip/hip_runtime.h>
#include <hip/hip_bf16.h>

#define DD 512
#define NN 8
#define LL0 128
#define LL1 256

// 2 * log2(e): pre-scale so tanh(t) needs only v_exp_f32 (2^x).
#define LOG2E2 2.8853900817779268f

typedef float f32x4 __attribute__((ext_vector_type(4)));
typedef __bf16 bf16x8 __attribute__((ext_vector_type(8)));

__device__ __forceinline__ float fexp2(float x) {
#if __has_builtin(__builtin_amdgcn_exp2f)
    return __builtin_amdgcn_exp2f(x);
#else
    float r; asm("v_exp_f32 %0, %1" : "=v"(r) : "v"(x)); return r;
#endif
}
__device__ __forceinline__ float frcp(float x) {
#if __has_builtin(__builtin_amdgcn_rcpf)
    return __builtin_amdgcn_rcpf(x);
#else
    float r; asm("v_rcp_f32 %0, %1" : "=v"(r) : "v"(x)); return r;
#endif
}

// sigma2(t2) = 1/(2^t2 + 1); tanh(t) = 1 - 2*sigma2(2*log2e*t).
__device__ __forceinline__ float sig2(float t2) {
    return frcp(fexp2(t2) + 1.0f);
}

// fp32 -> bf16 round-to-nearest-even (normals; inputs are well-scaled).
__device__ __forceinline__ unsigned short f2bf(float f) {
    unsigned int u = __float_as_uint(f);
    u += 0x7fffu + ((u >> 16) & 1u);
    return (unsigned short)(u >> 16);
}

// ---------------------------------------------------------------------------
// Kernel 0: convert x|m -> A16[3072][512] bf16, W -> W16[512][1024] bf16.
// 2048 blocks x 256 threads x 4 elems = 2,097,152 elems exactly.
// ---------------------------------------------------------------------------
__global__ __launch_bounds__(256) void cvt_kernel(
    const float* __restrict__ x, const float* __restrict__ m,
    const float* __restrict__ W,
    unsigned short* __restrict__ A16, unsigned short* __restrict__ W16)
{
    size_t i4 = ((size_t)blockIdx.x * 256 + threadIdx.x) * 4;
    const float* src;
    unsigned short* dst;
    if (i4 < (size_t)3072 * 512) {                 // A-part (x then m)
        src = (i4 < (size_t)1024 * 512) ? x + i4 : m + (i4 - (size_t)1024 * 512);
        dst = A16 + i4;
    } else {                                       // W-part
        size_t j = i4 - (size_t)3072 * 512;
        src = W + j; dst = W16 + j;
    }
    float4 v = *(const float4*)src;
    ushort4 o = make_ushort4(f2bf(v.x), f2bf(v.y), f2bf(v.z), f2bf(v.w));
    *(ushort4*)dst = o;
}

// ---------------------------------------------------------------------------
// Kernel 1: MFMA bf16 projection GEMM, fused bias + LOG2E2 epilogue.
//   xm[row][e] = LOG2E2 * (sum_k A16[row][k]*W16[e][koff+k] + (row<1024 ? Wb[e] : 0))
// Tile 128(M) x 64(e), K-step 64, 4 waves; per wave: 2x4 tiles of 16x16,
// 16x mfma_f32_16x16x32_bf16 per K-step. LDS rows padded to 72 bf16
// (144 B stride: 16B-aligned b128 reads, 2-way-free banks).
// Grid (8, 24) = 192 blocks.
// ---------------------------------------------------------------------------
__global__ __launch_bounds__(256) void mfma_proj_kernel(
    const unsigned short* __restrict__ A16, const unsigned short* __restrict__ W16,
    const float* __restrict__ Wb, float* __restrict__ xm)
{
    __shared__ unsigned short As[128][72];
    __shared__ unsigned short Bs[64][72];

    int e0   = blockIdx.x * 64;
    int row0 = blockIdx.y * 128;
    bool isx = row0 < (NN * LL0);
    int koff = isx ? 0 : DD;

    int tid  = threadIdx.x;
    int wid  = tid >> 6;            // wave 0..3 -> rows wid*32..+31
    int lane = tid & 63;
    int l15  = lane & 15, lk = lane >> 4;   // lk 0..3

    // staging maps
    int sar = tid >> 1, sak = (tid & 1) * 32;   // A: row 0..127, k 0/32
    int sbr = tid >> 2, sbk = (tid & 3) * 16;   // B: e 0..63, k 0,16,32,48

    const unsigned short* Ap = A16 + (size_t)(row0 + sar) * DD + sak;
    const unsigned short* Bp = W16 + (size_t)(e0 + sbr) * (2 * DD) + koff + sbk;

    uint4 a0 = *(const uint4*)(Ap);
    uint4 a1 = *(const uint4*)(Ap + 8);
    uint4 a2 = *(const uint4*)(Ap + 16);
    uint4 a3 = *(const uint4*)(Ap + 24);
    uint4 b0 = *(const uint4*)(Bp);
    uint4 b1 = *(const uint4*)(Bp + 8);

    f32x4 acc[2][4] = {};

    for (int kt = 0; kt < 8; ++kt) {
        if (kt) __syncthreads();    // prior step's LDS reads complete
        *(uint4*)&As[sar][sak + 0]  = a0;
        *(uint4*)&As[sar][sak + 8]  = a1;
        *(uint4*)&As[sar][sak + 16] = a2;
        *(uint4*)&As[sar][sak + 24] = a3;
        *(uint4*)&Bs[sbr][sbk + 0]  = b0;
        *(uint4*)&Bs[sbr][sbk + 8]  = b1;
        if (kt < 7) {               // prefetch next K-step
            int ko = (kt + 1) * 64;
            a0 = *(const uint4*)(Ap + ko);
            a1 = *(const uint4*)(Ap + ko + 8);
            a2 = *(const uint4*)(Ap + ko + 16);
            a3 = *(const uint4*)(Ap + ko + 24);
            b0 = *(const uint4*)(Bp + ko);
            b1 = *(const uint4*)(Bp + ko + 8);
        }
        __syncthreads();            // staged data visible

        #pragma unroll
        for (int kb = 0; kb < 2; ++kb) {
            bf16x8 af0 = *(const bf16x8*)&As[wid * 32 + l15][kb * 32 + lk * 8];
            bf16x8 af1 = *(const bf16x8*)&As[wid * 32 + 16 + l15][kb * 32 + lk * 8];
            #pragma unroll
            for (int ni = 0; ni < 4; ++ni) {
                bf16x8 bf = *(const bf16x8*)&Bs[ni * 16 + l15][kb * 32 + lk * 8];
                acc[0][ni] = __builtin_amdgcn_mfma_f32_16x16x32_bf16(af0, bf, acc[0][ni], 0, 0, 0);
                acc[1][ni] = __builtin_amdgcn_mfma_f32_16x16x32_bf16(af1, bf, acc[1][ni], 0, 0, 0);
            }
        }
    }

    // epilogue: C/D layout col = lane&15, row = (lane>>4)*4 + reg  [guide m89]
    #pragma unroll
    for (int ni = 0; ni < 4; ++ni) {
        int col = e0 + ni * 16 + l15;
        float bv = isx ? Wb[col] : 0.0f;
        #pragma unroll
        for (int mi = 0; mi < 2; ++mi) {
            #pragma unroll
            for (int r = 0; r < 4; ++r) {
                int row = row0 + wid * 32 + mi * 16 + lk * 4 + r;
                xm[(size_t)row * DD + col] = LOG2E2 * (acc[mi][ni][r] + bv);
            }
        }
    }
}

// ---------------------------------------------------------------------------
// Kernel 2: logits, staging from the single fused xm plane.
//   xs[d][a] = xm[x-row][d]; ms[d][b] = xm[m-row][d]   (scale/bias pre-applied)
//   wpart[dc][n][a][b] = sum_{d in chunk} V[d] * sig2(xs + ms)
// Tile 32a x 64b x 64d, 2a x 4b micro-tile. Grid (4, 32, 8) = 1024 = 4/CU.
// ---------------------------------------------------------------------------
__global__ __launch_bounds__(256, 4) void logits_kernel(
    const float* __restrict__ xm, const float* __restrict__ Vw,
    float* __restrict__ wpart)
{
    __shared__ __attribute__((aligned(16))) float xs[64][34];  // [d][a: 32+2]
    __shared__ __attribute__((aligned(16))) float ms[64][68];  // [d][b: 64+4]
    __shared__ __attribute__((aligned(16))) float vsh[64];

    int n  = blockIdx.z;
    int bt = blockIdx.x;          // 0..3 : 64 b-cols
    int at = blockIdx.y & 3;      // 0..3 : 32 a-rows
    int dc = blockIdx.y >> 2;     // 0..7 : 64-d chunk
    int tid = threadIdx.x;
    int ty = tid >> 4, tx = tid & 15;

    // ---- stage x-part: 32 rows x 64 d
    {
        int r  = tid & 31;
        int c8 = (tid >> 5) * 8;
        const float* src = xm + ((size_t)(n * LL0 + at * 32) + r) * DD + dc * 64 + c8;
        float4 v0 = *(const float4*)(src);
        float4 v1 = *(const float4*)(src + 4);
        xs[c8 + 0][r] = v0.x; xs[c8 + 1][r] = v0.y;
        xs[c8 + 2][r] = v0.z; xs[c8 + 3][r] = v0.w;
        xs[c8 + 4][r] = v1.x; xs[c8 + 5][r] = v1.y;
        xs[c8 + 6][r] = v1.z; xs[c8 + 7][r] = v1.w;
    }
    // ---- stage m-part: 64 rows x 64 d (m-rows start at xm row 1024)
    {
        int r   = tid & 63;
        int c16 = (tid >> 6) * 16;
        const float* src = xm + ((size_t)(NN * LL0 + n * LL1 + bt * 64) + r) * DD
                           + dc * 64 + c16;
        #pragma unroll
        for (int q = 0; q < 4; ++q) {
            float4 p = *(const float4*)(src + q * 4);
            int c = c16 + q * 4;
            ms[c + 0][r] = p.x; ms[c + 1][r] = p.y;
            ms[c + 2][r] = p.z; ms[c + 3][r] = p.w;
        }
        if (tid < 16)
            *(float4*)&vsh[tid * 4] = *(const float4*)(Vw + dc * 64 + tid * 4);
    }
    __syncthreads();

    float acc[2][4] = {};

    #pragma unroll 8
    for (int kk = 0; kk < 64; ++kk) {
        float2 xa = *(const float2*)&xs[kk][ty * 2];
        float4 mb = *(const float4*)&ms[kk][tx * 4];
        float  vv = vsh[kk];
        float b_[4] = {mb.x, mb.y, mb.z, mb.w};
        #pragma unroll
        for (int j = 0; j < 4; ++j) {
            acc[0][j] = fmaf(vv, sig2(xa.x + b_[j]), acc[0][j]);
            acc[1][j] = fmaf(vv, sig2(xa.y + b_[j]), acc[1][j]);
        }
    }

    const size_t P = (size_t)NN * LL0 * LL1;
    float* wp = wpart + (size_t)dc * P
              + ((size_t)n * LL0 + at * 32 + ty * 2) * LL1 + bt * 64 + tx * 4;
    *(float4*)(wp)       = make_float4(acc[0][0], acc[0][1], acc[0][2], acc[0][3]);
    *(float4*)(wp + LL1) = make_float4(acc[1][0], acc[1][1], acc[1][2], acc[1][3]);
}

// ---------------------------------------------------------------------------
// Kernel 3: masked softmax over b (sums 8 d-chunk partials, -2 scale).
// ---------------------------------------------------------------------------
__global__ __launch_bounds__(256) void softmax_kernel(
    float* __restrict__ wpart, const int* __restrict__ mask)
{
    __shared__ float red[4];
    __shared__ float red2[4];
    const size_t P = (size_t)NN * LL0 * LL1;
    int row = blockIdx.x;          // n*L0 + a
    int n = row >> 7;
    int b = threadIdx.x;
    size_t idx = (size_t)row * LL1 + b;

    float s8 = 0.f;
    #pragma unroll
    for (int p = 0; p < 8; ++p) s8 += wpart[idx + (size_t)p * P];
    float w = -2.0f * s8;
    if (mask[n * LL1 + b] == 0) w = -1e30f;

    float mx = w;
    #pragma unroll
    for (int off = 32; off; off >>= 1) mx = fmaxf(mx, __shfl_xor(mx, off));
    int wv = threadIdx.x >> 6;
    if ((threadIdx.x & 63) == 0) red[wv] = mx;
    __syncthreads();
    mx = fmaxf(fmaxf(red[0], red[1]), fmaxf(red[2], red[3]));

    float e = (w > -1e29f) ? __expf(w - mx) : 0.f;
    float s = e;
    #pragma unroll
    for (int off = 32; off; off >>= 1) s += __shfl_xor(s, off);
    if ((threadIdx.x & 63) == 0) red2[wv] = s;
    __syncthreads();
    s = red2[0] + red2[1] + red2[2] + red2[3];

    wpart[idx] = e / s;            // dense write into plane 0 (reads done first)
}

// ---------------------------------------------------------------------------
// Kernel 4: v[n,a,d] = sum_b w[n,a,b] * m[n,b,d].
// Tile 32a x 64d, K-chunk 32, 2a x 4d micro-tile. Grid (8,4,8) = 256 = 1/CU.
// ---------------------------------------------------------------------------
__global__ __launch_bounds__(256, 4) void vgemm_kernel(
    const float* __restrict__ wbuf, const float* __restrict__ m,
    float* __restrict__ out)
{
    __shared__ float wt[32][36];   // [k][a: 32+4]
    __shared__ float mt[32][68];   // [k][d: 64+4]

    int n  = blockIdx.z;
    int a0 = blockIdx.y * 32;
    int d0 = blockIdx.x * 64;
    int tid = threadIdx.x;
    int ty = tid >> 4, tx = tid & 15;

    const float* wrow = wbuf + ((size_t)n * LL0 + a0) * LL1;
    const float* mrow = m + (size_t)n * LL1 * DD;

    float acc[2][4] = {};
    for (int k0 = 0; k0 < LL1; k0 += 32) {
        {
            int r  = tid >> 3;            // a-row 0..31
            int c4 = (tid & 7) * 4;       // k 0..28
            float4 wv = *(const float4*)(wrow + (size_t)r * LL1 + k0 + c4);
            wt[c4 + 0][r] = wv.x; wt[c4 + 1][r] = wv.y;
            wt[c4 + 2][r] = wv.z; wt[c4 + 3][r] = wv.w;
        }
        {
            int r  = tid >> 3;            // k-row 0..31
            int c8 = (tid & 7) * 8;       // d 0..56
            const float* src = mrow + (size_t)(k0 + r) * DD + d0 + c8;
            *(float4*)&mt[r][c8]     = *(const float4*)(src);
            *(float4*)&mt[r][c8 + 4] = *(const float4*)(src + 4);
        }
        __syncthreads();
        #pragma unroll 8
        for (int kk = 0; kk < 32; ++kk) {
            float2 av = *(const float2*)&wt[kk][ty * 2];
            float4 bv = *(const float4*)&mt[kk][tx * 4];
            acc[0][0] = fmaf(av.x, bv.x, acc[0][0]);
            acc[0][1] = fmaf(av.x, bv.y, acc[0][1]);
            acc[0][2] = fmaf(av.x, bv.z, acc[0][2]);
            acc[0][3] = fmaf(av.x, bv.w, acc[0][3]);
            acc[1][0] = fmaf(av.y, bv.x, acc[1][0]);
            acc[1][1] = fmaf(av.y, bv.y, acc[1][1]);
            acc[1][2] = fmaf(av.y, bv.z, acc[1][2]);
            acc[1][3] = fmaf(av.y, bv.w, acc[1][3]);
        }
        __syncthreads();
    }
    float* op = out + ((size_t)n * LL0 + a0 + ty * 2) * DD + d0 + tx * 4;
    *(float4*)(op)      = make_float4(acc[0][0], acc[0][1], acc[0][2], acc[0][3]);
    *(float4*)(op + DD) = make_float4(acc[1][0], acc[1][1], acc[1][2], acc[1][3]);
}

extern "C" void kernel_launch(void* const* d_in, const int* in_sizes, int n_in,
                              void* d_out, int out_size, void* d_ws, size_t ws_size,
                              hipStream_t stream) {
    const float* x    = (const float*)d_in[0];
    const float* m    = (const float*)d_in[1];
    const int*   mask = (const int*)d_in[2];
    const float* W_w  = (const float*)d_in[3];
    const float* W_b  = (const float*)d_in[4];
    const float* V_w  = (const float*)d_in[5];
    const float* V_b  = (const float*)d_in[6];
    (void)V_b; // additive constant — cancels under softmax shift-invariance
    float* out = (float*)d_out;

    // Workspace (floats):
    //   xm    : 3072*512              = 1,572,864  (fused scaled/biased projections)
    //   wpart : 8 * 8*128*256         = 2,097,152  (logit partials; plane 0 -> w)
    //   A16   : 3072*512 bf16         =   786,432  float-equiv
    //   W16   : 512*1024 bf16         =   262,144  float-equiv
    // Total: 4,718,592 floats = 18.9 MB
    float* xm    = (float*)d_ws;
    float* wpart = xm + (size_t)3072 * 512;
    unsigned short* A16 = (unsigned short*)(wpart + (size_t)8 * NN * LL0 * LL1);
    unsigned short* W16 = A16 + (size_t)3072 * 512;

    cvt_kernel<<<dim3(2048), 256, 0, stream>>>(x, m, W_w, A16, W16);
    mfma_proj_kernel<<<dim3(8, 24), 256, 0, stream>>>(A16, W16, W_b, xm);
    logits_kernel<<<dim3(4, 32, 8), 256, 0, stream>>>(xm, V_w, wpart);
    softmax_kernel<<<dim3(1024), 256, 0, stream>>>(wpart, mask);
    vgemm_kernel<<<dim3(8, 4, 8), 256, 0, stream>>>(wpart, m, out);
}